// Round 1
// baseline (955.365 us; speedup 1.0000x reference)
//
#include <hip/hip_runtime.h>
#include <hip/hip_bf16.h>
#include <stdint.h>

#define M_TOT 8192
#define N_TOT 16384
#define K_TOT 4096

typedef int v4i __attribute__((ext_vector_type(4)));

__device__ __forceinline__ float fix_scale(float s) { return s == 0.0f ? 1.0f : s; }

__device__ __forceinline__ void gload_lds16(const void* g, void* l) {
    __builtin_amdgcn_global_load_lds((__attribute__((address_space(1))) void*)g,
                                     (__attribute__((address_space(3))) void*)l,
                                     16, 0, 0);
}

__device__ __forceinline__ int8_t quant1(float x, float scale) {
    float r = fminf(127.0f, fmaxf(-127.0f, rintf(x / scale)));
    return (int8_t)(int)r;
}

// ---------------- lhs: per-row absmax quantize ----------------
__global__ __launch_bounds__(256) void k_quant_lhs(const float* __restrict__ x,
                                                   int8_t* __restrict__ q,
                                                   float* __restrict__ s) {
    const int row = blockIdx.x;
    const int t = threadIdx.x;
    const float* xr = x + (size_t)row * K_TOT;
    float4 v[4];
    float m = 0.0f;
#pragma unroll
    for (int i = 0; i < 4; ++i) {
        v[i] = ((const float4*)xr)[i * 256 + t];
        m = fmaxf(m, fmaxf(fmaxf(fabsf(v[i].x), fabsf(v[i].y)),
                           fmaxf(fabsf(v[i].z), fabsf(v[i].w))));
    }
#pragma unroll
    for (int off = 32; off; off >>= 1) m = fmaxf(m, __shfl_xor(m, off));
    __shared__ float wmax[4];
    if ((t & 63) == 0) wmax[t >> 6] = m;
    __syncthreads();
    m = fmaxf(fmaxf(wmax[0], wmax[1]), fmaxf(wmax[2], wmax[3]));
    const float scale = fix_scale(m / 127.0f);
    if (t == 0) s[row] = scale;
    unsigned* qrow = (unsigned*)(q + (size_t)row * K_TOT);
#pragma unroll
    for (int i = 0; i < 4; ++i) {
        unsigned b0 = (unsigned char)quant1(v[i].x, scale);
        unsigned b1 = (unsigned char)quant1(v[i].y, scale);
        unsigned b2 = (unsigned char)quant1(v[i].z, scale);
        unsigned b3 = (unsigned char)quant1(v[i].w, scale);
        qrow[i * 256 + t] = b0 | (b1 << 8) | (b2 << 16) | (b3 << 24);
    }
}

// ---------------- rhs: per-column absmax (atomicMax on float bits) ----------------
__global__ __launch_bounds__(256) void k_rhs_absmax(const float* __restrict__ rhs,
                                                    unsigned* __restrict__ amax) {
    const int f = blockIdx.x * 256 + threadIdx.x;
    const int d0 = blockIdx.y * 256;
    const float* p = rhs + (size_t)d0 * N_TOT + f;
    float m = 0.0f;
#pragma unroll 4
    for (int d = 0; d < 256; ++d)
        m = fmaxf(m, fabsf(p[(size_t)d * N_TOT]));
    atomicMax(amax + f, __float_as_uint(m));
}

__global__ __launch_bounds__(256) void k_rhs_scale(const unsigned* __restrict__ amax,
                                                   float* __restrict__ s) {
    const int f = blockIdx.x * 256 + threadIdx.x;
    s[f] = fix_scale(__uint_as_float(amax[f]) / 127.0f);
}

// ---------------- rhs: quantize + transpose to [N][K] ----------------
__global__ __launch_bounds__(256) void k_quant_rhs_t(const float* __restrict__ rhs,
                                                     const float* __restrict__ s,
                                                     int8_t* __restrict__ qT) {
    const int f0 = blockIdx.x * 64;
    const int d0 = blockIdx.y * 64;
    const int t = threadIdx.x;
    __shared__ float sc[64];
    __shared__ alignas(16) int8_t tile[64][64];  // [f local][d local]
    if (t < 64) sc[t] = s[f0 + t];
    __syncthreads();
    const int fl = (t & 15) * 4;
    const int rl = t >> 4;
#pragma unroll
    for (int i = 0; i < 4; ++i) {
        const int dl = i * 16 + rl;
        float4 v = *(const float4*)(rhs + (size_t)(d0 + dl) * N_TOT + f0 + fl);
        tile[fl + 0][dl] = quant1(v.x, sc[fl + 0]);
        tile[fl + 1][dl] = quant1(v.y, sc[fl + 1]);
        tile[fl + 2][dl] = quant1(v.z, sc[fl + 2]);
        tile[fl + 3][dl] = quant1(v.w, sc[fl + 3]);
    }
    __syncthreads();
    const int fr = t >> 2;
    const int dc = (t & 3) * 16;
    *(int4*)(qT + (size_t)(f0 + fr) * K_TOT + d0 + dc) = *(const int4*)&tile[fr][dc];
}

// ---------------- int8 GEMM: C[m][n] = acc(i32) * sA[m] * sB[n] ----------------
#define BM 128
#define BN 128
#define BK 64
#define NKT (K_TOT / BK)

__global__ __launch_bounds__(256) void k_gemm(const int8_t* __restrict__ qA,   // [M][K]
                                              const int8_t* __restrict__ qB,   // [N][K]
                                              const float* __restrict__ sA,
                                              const float* __restrict__ sB,
                                              float* __restrict__ C) {
    __shared__ alignas(16) int8_t As[2][BM * BK];
    __shared__ alignas(16) int8_t Bs[2][BN * BK];

    const int bn0 = blockIdx.x * BN;
    const int bm0 = blockIdx.y * BM;
    const int tid = threadIdx.x;
    const int wave = tid >> 6;
    const int lane = tid & 63;
    const int wm = (wave >> 1) * 64;
    const int wn = (wave & 1) * 64;

    const int flat0 = wave * 1024 + lane * 16;

    v4i acc[4][4];
#pragma unroll
    for (int i = 0; i < 4; ++i)
#pragma unroll
        for (int j = 0; j < 4; ++j) {
            v4i z = {0, 0, 0, 0};
            acc[i][j] = z;
        }

    auto stage = [&](int buf, int kt) {
        const int k0 = kt * BK;
#pragma unroll
        for (int i = 0; i < 2; ++i) {
            const int flat = i * 4096 + flat0;
            const int row = flat >> 6;
            const int col = flat & 63;
            gload_lds16(qA + (size_t)(bm0 + row) * K_TOT + k0 + col,
                        &As[buf][i * 4096 + wave * 1024]);
            gload_lds16(qB + (size_t)(bn0 + row) * K_TOT + k0 + col,
                        &Bs[buf][i * 4096 + wave * 1024]);
        }
    };

    stage(0, 0);
    __syncthreads();

    const int frow = lane & 15;       // row within 16x16 tile
    const int fcol = (lane >> 4) * 16;  // byte col (k) within BK

    for (int kt = 0; kt < NKT; ++kt) {
        const int buf = kt & 1;
        if (kt + 1 < NKT) stage(buf ^ 1, kt + 1);
        v4i af[4], bf[4];
#pragma unroll
        for (int i = 0; i < 4; ++i) {
            af[i] = *(const v4i*)&As[buf][(wm + i * 16 + frow) * BK + fcol];
            bf[i] = *(const v4i*)&Bs[buf][(wn + i * 16 + frow) * BK + fcol];
        }
#pragma unroll
        for (int i = 0; i < 4; ++i)
#pragma unroll
            for (int j = 0; j < 4; ++j)
                acc[i][j] = __builtin_amdgcn_mfma_i32_16x16x64_i8(af[i], bf[j], acc[i][j], 0, 0, 0);
        __syncthreads();
    }

    // epilogue: dequant + store
    const int cr = (lane >> 4) * 4;  // row offset within 16x16 C tile
    const int cc = lane & 15;        // col within tile
#pragma unroll
    for (int i = 0; i < 4; ++i) {
        const int gr0 = bm0 + wm + i * 16 + cr;
#pragma unroll
        for (int j = 0; j < 4; ++j) {
            const int gc = bn0 + wn + j * 16 + cc;
            const float sb = sB[gc];
#pragma unroll
            for (int r = 0; r < 4; ++r) {
                const int gr = gr0 + r;
                C[(size_t)gr * N_TOT + gc] = (float)acc[i][j][r] * sA[gr] * sb;
            }
        }
    }
}

extern "C" void kernel_launch(void* const* d_in, const int* in_sizes, int n_in,
                              void* d_out, int out_size, void* d_ws, size_t ws_size,
                              hipStream_t stream) {
    const float* lhs = (const float*)d_in[0];
    const float* rhs = (const float*)d_in[1];
    float* out = (float*)d_out;
    char* ws = (char*)d_ws;

    int8_t* qA = (int8_t*)ws;                                   // 32 MB
    int8_t* qB = (int8_t*)(ws + (size_t)33554432);              // 64 MB
    float* sA = (float*)(ws + (size_t)33554432 + 67108864);     // 32 KB
    float* sB = sA + M_TOT;                                     // 64 KB
    unsigned* amax = (unsigned*)(sB + N_TOT);                   // 64 KB

    hipMemsetAsync(amax, 0, N_TOT * sizeof(unsigned), stream);

    k_quant_lhs<<<M_TOT, 256, 0, stream>>>(lhs, qA, sA);
    k_rhs_absmax<<<dim3(N_TOT / 256, K_TOT / 256), 256, 0, stream>>>(rhs, amax);
    k_rhs_scale<<<N_TOT / 256, 256, 0, stream>>>(amax, sB);
    k_quant_rhs_t<<<dim3(N_TOT / 64, K_TOT / 64), 256, 0, stream>>>(rhs, sB, qB);
    k_gemm<<<dim3(N_TOT / BN, M_TOT / BM), 256, 0, stream>>>(qA, qB, sA, sB, out);
}